// Round 18
// baseline (1726.603 us; speedup 1.0000x reference)
//
#include <hip/hip_runtime.h>

#define VV 32000
#define EE 256
#define HH 512
#define BB 32
#define SS 80
#define TT 80
// decoder rows = B*(T-1) = 2528, padded to 2560 (20 tiles of 128)

typedef __attribute__((ext_vector_type(8))) _Float16 half8;
typedef __attribute__((ext_vector_type(4))) _Float16 half4;
typedef __attribute__((ext_vector_type(4))) float floatx4;
typedef unsigned long long u64;

__device__ __forceinline__ void gload16(const _Float16* g, _Float16* l) {
  __builtin_amdgcn_global_load_lds((const __attribute__((address_space(1))) void*)g,
                                   (__attribute__((address_space(3))) void*)l, 16, 0, 0);
}

__device__ __forceinline__ u64 aload(const u64* p) {
  return __hip_atomic_load(p, __ATOMIC_RELAXED, __HIP_MEMORY_SCOPE_AGENT);
}
__device__ __forceinline__ void astore(u64* p, u64 v) {
  __hip_atomic_store(p, v, __ATOMIC_RELAXED, __HIP_MEMORY_SCOPE_AGENT);
}
// sc0 load: L1-bypass, hits the XCD-shared L2 (fast intra-XCD path)
__device__ __forceinline__ u64 ld_sc0(const u64* p) {
  u64 v;
  asm volatile("global_load_dwordx2 %0, %1, off sc0\n\ts_waitcnt vmcnt(0)"
               : "=v"(v) : "v"(p) : "memory");
  return v;
}

// ---- 15-bit packing (r9-proven): |h|<=1 so fp16 bit14 (exp MSB) is 0 -------
__device__ __forceinline__ unsigned pack15(unsigned short u) {
  return (u & 0x3FFFu) | ((u >> 1) & 0x4000u);
}
__device__ __forceinline__ unsigned short unpack15(unsigned v) {
  return (unsigned short)((v & 0x3FFFu) | ((v & 0x4000u) << 1));
}
__device__ __forceinline__ u64 unpack_word4(u64 a) {  // -> 4 fp16 in a u64
  u64 o = 0;
#pragma unroll
  for (int i = 0; i < 4; ++i)
    o |= (u64)unpack15((unsigned)(a >> (15*i)) & 0x7FFFu) << (16*i);
  return o;
}

__device__ __forceinline__ float dot8(half8 a, half8 b, float c) {
  typedef __attribute__((ext_vector_type(2))) _Float16 half2v;
  half2v a0 = {a[0],a[1]}, a1 = {a[2],a[3]}, a2 = {a[4],a[5]}, a3 = {a[6],a[7]};
  half2v b0 = {b[0],b[1]}, b1 = {b[2],b[3]}, b2 = {b[4],b[5]}, b3 = {b[6],b[7]};
  c = __builtin_amdgcn_fdot2(a0, b0, c, false);
  c = __builtin_amdgcn_fdot2(a1, b1, c, false);
  c = __builtin_amdgcn_fdot2(a2, b2, c, false);
  c = __builtin_amdgcn_fdot2(a3, b3, c, false);
  return c;
}

__device__ __forceinline__ float sigm(float x) { return 1.f/(1.f + __expf(-x)); }
__device__ __forceinline__ float tanh_f(float x) { return 2.f/(1.f + __expf(-2.f*x)) - 1.f; }

// ---------------- prep: gi GEMMs + oWh conversion + hx init, ONE launch ------
// blocks 0..479: gi GEMM (p%24<12 -> encoder, else decoder), r16-proven path.
// blocks 480..991: outW fp32 -> fp16 elementwise.
// blocks 992..995: zero hx via sc1 (LLC-visible for seq_pb's fallback path).
__global__ __launch_bounds__(256) void prep_all(
    const int* __restrict__ src, const int* __restrict__ tgt,
    const float* __restrict__ emb,
    const float* __restrict__ eWih, const float* __restrict__ ebih,
    const float* __restrict__ dWih, const float* __restrict__ dbih,
    const float* __restrict__ outW, _Float16* __restrict__ oWh,
    float* __restrict__ giE, float* __restrict__ giD,
    u64* __restrict__ hx)
{
  const int pblk = blockIdx.x;
  const int tid = threadIdx.x;

  if (pblk >= 992) {                 // ---- hx zero-init (8192 u64 words) ----
    const int pid = pblk - 992;      // 0..3
    for (int i = pid*256 + tid; i < 8192; i += 4*256) astore(hx + i, 0ull);
    return;
  }
  if (pblk >= 480) {                 // ---- oWh conversion path ----
    const int pid = pblk - 480;      // 0..511
    const long total8 = (long)VV*1024/8;
    for (long i = (long)pid*256 + tid; i < total8; i += 512L*256) {
      const float* s_ = outW + i*8;
      const floatx4 a = *(const floatx4*)s_;
      const floatx4 b = *(const floatx4*)(s_ + 4);
      half8 h;
      h[0]=(_Float16)a[0]; h[1]=(_Float16)a[1]; h[2]=(_Float16)a[2]; h[3]=(_Float16)a[3];
      h[4]=(_Float16)b[0]; h[5]=(_Float16)b[1]; h[6]=(_Float16)b[2]; h[7]=(_Float16)b[3];
      *(half8*)(oWh + i*8) = h;
    }
    return;
  }

  // ---- gi GEMM path (r16-proven) ----
  __shared__ _Float16 As[4096];
  __shared__ _Float16 Bs[4096];
  const int lane = tid & 63;
  const int wv = tid >> 6;
  const int wr = wv >> 1, wc = wv & 1;
  const int mt = pblk / 24;
  const int ntx = pblk % 24;
  const bool isE = ntx < 12;
  const int nt = isE ? ntx : ntx - 12;
  const float* Wih = isE ? eWih : dWih;
  const float* bih = isE ? ebih : dbih;
  float* gi = isE ? giE : giD;
  floatx4 acc[4][4];
#pragma unroll
  for (int i=0;i<4;++i)
#pragma unroll
    for (int j=0;j<4;++j) acc[i][j] = (floatx4){0.f,0.f,0.f,0.f};
  const int r2 = tid >> 1, cb = (tid & 1) * 16;
  const int R = mt*128 + r2;
  int tok = -1;
  if (isE) tok = src[R];
  else if (R < 2528) { const int b_ = R/79, tt = R - b_*79; tok = tgt[b_*80 + tt]; }
  const float* arow = (tok >= 0) ? emb + (size_t)tok*EE : nullptr;
  const float* brow = Wih + (size_t)(nt*128 + r2)*EE;
  const int g8 = (lane >> 4) * 8;
  const int lr = lane & 15;
  for (int kb = 0; kb < EE; kb += 32) {
    __syncthreads();
    if (arow) {
#pragma unroll
      for (int q = 0; q < 4; ++q) {
        const floatx4 va = *(const floatx4*)(arow + kb + cb + q*4);
#pragma unroll
        for (int e = 0; e < 4; ++e) As[r2*32 + cb + q*4 + e] = (_Float16)va[e];
      }
    } else {
#pragma unroll
      for (int q = 0; q < 16; ++q) As[r2*32 + cb + q] = (_Float16)0.f;
    }
#pragma unroll
    for (int q = 0; q < 4; ++q) {
      const floatx4 vb = *(const floatx4*)(brow + kb + cb + q*4);
#pragma unroll
      for (int e = 0; e < 4; ++e) Bs[r2*32 + cb + q*4 + e] = (_Float16)vb[e];
    }
    __syncthreads();
    half8 af[4], bf[4];
#pragma unroll
    for (int i=0;i<4;++i) af[i] = *(const half8*)(As + (wr*64 + i*16 + lr)*32 + g8);
#pragma unroll
    for (int j=0;j<4;++j) bf[j] = *(const half8*)(Bs + (wc*64 + j*16 + lr)*32 + g8);
#pragma unroll
    for (int i=0;i<4;++i)
#pragma unroll
      for (int j=0;j<4;++j)
        acc[i][j] = __builtin_amdgcn_mfma_f32_16x16x32_f16(af[i], bf[j], acc[i][j], 0,0,0);
  }
  const int rm = 4*(lane>>4);
#pragma unroll
  for (int i=0;i<4;++i)
#pragma unroll
    for (int r=0;r<4;++r) {
      const int row = mt*128 + wr*64 + i*16 + rm + r;
      if (isE || row < 2528) {
#pragma unroll
        for (int j=0;j<4;++j) {
          const int col = nt*128 + wc*64 + j*16 + lr;
          gi[(size_t)row*1536 + col] = acc[i][j][r] + bih[col];
        }
      }
    }
}

// ---------------- logits GEMM, XCD-clustered (EXACT r12/r15; proven) ---------
__global__ __launch_bounds__(256) void logits_gemm(
    const _Float16* __restrict__ A, const _Float16* __restrict__ Bm,
    const float* __restrict__ bias, float* __restrict__ out)
{
  const int p = blockIdx.x;
  const int x = p & 7, s = p >> 3;
  const int nt = x + 8*(s / 20);
  const int mt = s % 20;
  if (nt >= 250) return;
  __shared__ _Float16 As[4096];
  __shared__ _Float16 Bs[4096];
  const int tid = threadIdx.x;
  const int lane = tid & 63;
  const int wv = tid >> 6;
  const int wr = wv >> 1, wc = wv & 1;
  floatx4 acc[4][4];
#pragma unroll
  for (int i=0;i<4;++i)
#pragma unroll
    for (int j=0;j<4;++j) acc[i][j] = (floatx4){0.f,0.f,0.f,0.f};
  const int srow = lane >> 2;
  const int scol = (lane & 3) * 8;
  const _Float16* Ab = A + (size_t)(mt*128)*1024;
  const _Float16* Bb = Bm + (size_t)(nt*128)*1024;
  const int g8 = (lane >> 4) * 8;
  const int lr = lane & 15;
  for (int kb = 0; kb < 1024; kb += 32) {
    __syncthreads();
#pragma unroll
    for (int cc = 0; cc < 2; ++cc) {
      const int c = wv*2 + cc;
      gload16(Ab + (size_t)(c*16 + srow)*1024 + kb + scol, As + c*512);
      gload16(Bb + (size_t)(c*16 + srow)*1024 + kb + scol, Bs + c*512);
    }
    __syncthreads();
    half8 af[4], bf[4];
#pragma unroll
    for (int i=0;i<4;++i) af[i] = *(const half8*)(As + (wr*64 + i*16 + lr)*32 + g8);
#pragma unroll
    for (int j=0;j<4;++j) bf[j] = *(const half8*)(Bs + (wc*64 + j*16 + lr)*32 + g8);
#pragma unroll
    for (int i=0;i<4;++i)
#pragma unroll
      for (int j=0;j<4;++j)
        acc[i][j] = __builtin_amdgcn_mfma_f32_16x16x32_f16(af[i], bf[j], acc[i][j], 0,0,0);
  }
  const int rm = 4*(lane>>4);
#pragma unroll
  for (int i=0;i<4;++i)
#pragma unroll
    for (int r=0;r<4;++r) {
      const int row = mt*128 + wr*64 + i*16 + rm + r;
#pragma unroll
      for (int j=0;j<4;++j) {
        const int col = nt*128 + wc*64 + j*16 + lr;
        if (row < 2528) {
          const int b = row / 79;
          const int t = row - b*79;
          out[(size_t)(b*80 + t + 1)*VV + col] = acc[i][j][r] + bias[col];
        } else {
          out[(size_t)((row - 2528)*80)*VV + col] = 0.f;
        }
      }
    }
}

// ---------------- per-batch decoupled recurrence, HYBRID exchange ------------
// r15 structure (proven 645us) with placement-adaptive exchange:
//   publish: plain u64 store (dirties the XCD-shared L2 -- same-XCD fast
//            path; blockIdx%8 cycling puts batch b's 8 WGs on one XCD) +
//            sc1 store of the SAME value (LLC, coherent under any placement).
//   consume: sc0 polls (L1-bypass, L2-hit); after 64 misses fall back to the
//            r15 sc1 poll. Tag-in-data self-validates; u64 stores atomic;
//            correctness placement-independent (G16), only speed varies.
#define SEQ_SMEM (80*512*2 + 512*2 + 512*2 + 3*64*8*4 + 2*80*4)
__global__ __launch_bounds__(512) void seq_pb(
    const float* __restrict__ eWhh, const float* __restrict__ dWhh,
    const float* __restrict__ ebhh, const float* __restrict__ dbhh,
    const float* __restrict__ giE, const float* __restrict__ giD,
    u64* __restrict__ hx,          // [2][32][128] u64, zeroed by prep_all
    _Float16* __restrict__ comb)
{
  extern __shared__ char smem[];
  _Float16* eo_l = (_Float16*)smem;          // [80][512]
  _Float16* hbuf = eo_l + 80*512;            // [512]
  _Float16* hatt = hbuf + 512;               // [512]
  float* part = (float*)(hatt + 512);        // [3][64][8]
  float* sc = part + 3*64*8;                 // [80]
  float* aw = sc + 80;                       // [80]

  const int bi = blockIdx.x;
  const int q = bi >> 5, b = bi & 31;
  const int tid = threadIdx.x;
  const int lane = tid & 63;
  const int wv = tid >> 6;
  const int jl = tid & 63;        // local col
  const int kq = tid >> 6;        // k-chunk 0..7
  const int j  = q*64 + jl;       // global col

  half8 wreg[3][8];               // register-resident weights
  auto loadW = [&](const float* W){
#pragma unroll
    for (int g = 0; g < 3; ++g)
#pragma unroll
      for (int c = 0; c < 8; ++c) {
        const float* s8 = W + ((size_t)(g*512 + j))*512 + kq*64 + c*8;
        const floatx4 a = *(const floatx4*)s8;
        const floatx4 d = *(const floatx4*)(s8 + 4);
        half8 h;
        h[0]=(_Float16)a[0]; h[1]=(_Float16)a[1]; h[2]=(_Float16)a[2]; h[3]=(_Float16)a[3];
        h[4]=(_Float16)d[0]; h[5]=(_Float16)d[1]; h[6]=(_Float16)d[2]; h[7]=(_Float16)d[3];
        wreg[g][c] = h;
      }
  };

  auto consume = [&](int slotR, u64 rtag){
    if (tid < 112) {               // 112 partner words; own 16 words stay local
      const int m = tid + (tid >= q*16 ? 16 : 0);
      const u64* sp = hx + (size_t)slotR*4096 + b*128 + m;
      u64 v;
      int fast = 64;
      for (;;) {
        v = ld_sc0(sp);                      // L2 fast path
        if ((v >> 60) == rtag) break;
        if (--fast == 0) {                   // coherent fallback (r15 path)
          v = aload(sp);
          int guard = 0;
          while ((v >> 60) != rtag && guard < (1<<22)) { v = aload(sp); ++guard; }
          break;
        }
      }
      *(u64*)&hbuf[m*4] = unpack_word4(v);
    }
    __syncthreads();
  };
  auto publish = [&](int slotW, u64 wtag){
    if (tid < 16) {
      const int m = q*16 + tid;
      u64 wq = wtag << 60;
#pragma unroll
      for (int e = 0; e < 4; ++e) {
        union { _Float16 h; unsigned short u; } cv; cv.h = hbuf[m*4 + e];
        wq |= (u64)pack15(cv.u) << (15*e);
      }
      u64* gp = hx + (size_t)slotW*4096 + b*128 + m;
      *(volatile u64*)gp = wq;               // fast path: XCD-shared L2
      astore(gp, wq);                        // coherent: LLC (same value)
    }
  };

  float hp = 0.f;                 // fp32 h_prev for col j (tid<64 only)
  auto gru = [&](float gr_, float gz_, float gn_, float bR, float bZ, float bN){
    half8 hv[8];
#pragma unroll
    for (int c = 0; c < 8; ++c) hv[c] = *(const half8*)&hbuf[kq*64 + c*8];
    float p0 = 0.f, p1 = 0.f, p2 = 0.f;
#pragma unroll
    for (int c = 0; c < 8; ++c) {
      p0 = dot8(wreg[0][c], hv[c], p0);
      p1 = dot8(wreg[1][c], hv[c], p1);
      p2 = dot8(wreg[2][c], hv[c], p2);
    }
    part[(0*64 + jl)*8 + kq] = p0;
    part[(1*64 + jl)*8 + kq] = p1;
    part[(2*64 + jl)*8 + kq] = p2;
    __syncthreads();
    if (tid < 64) {
      float a0 = 0.f, a1 = 0.f, a2 = 0.f;
#pragma unroll
      for (int e = 0; e < 8; ++e) {
        a0 += part[(0*64 + tid)*8 + e];
        a1 += part[(1*64 + tid)*8 + e];
        a2 += part[(2*64 + tid)*8 + e];
      }
      const float rg = sigm(gr_ + a0 + bR);
      const float zg = sigm(gz_ + a1 + bZ);
      const float ng = tanh_f(gn_ + rg*(a2 + bN));
      const float hn = (1.f - zg)*ng + zg*hp;     // |hn| <= 1 by induction
      hp = hn;
      hbuf[q*64 + tid] = (_Float16)hn;
    }
    __syncthreads();
  };

  auto attention = [&](int trow){
    const half8 hf = *(const half8*)&hatt[lane*8];
#pragma unroll 2
    for (int i = 0; i < 10; ++i) {               // 8 waves x 10 scores
      const int s = wv*10 + i;
      const half8 ev = *(const half8*)&eo_l[s*512 + lane*8];
      float pt = dot8(ev, hf, 0.f);
#pragma unroll
      for (int o = 32; o; o >>= 1) pt += __shfl_xor(pt, o);
      if (lane == 0) sc[s] = pt;
    }
    __syncthreads();
    if (wv == 0) {                               // softmax over 80 (wave 0)
      const float v0 = sc[lane];
      const float v1 = (lane < 16) ? sc[64+lane] : -1e30f;
      float m = fmaxf(v0, v1);
#pragma unroll
      for (int o = 32; o; o >>= 1) m = fmaxf(m, __shfl_xor(m, o));
      const float e0 = __expf(v0 - m);
      const float e1 = (lane < 16) ? __expf(v1 - m) : 0.f;
      float ssum = e0 + e1;
#pragma unroll
      for (int o = 32; o; o >>= 1) ssum += __shfl_xor(ssum, o);
      const float inv = 1.f/ssum;
      aw[lane] = e0*inv;
      if (lane < 16) aw[64+lane] = e1*inv;
    }
    __syncthreads();
    if (tid < 64) {                              // own 64 ctx cols
      float c = 0.f;
#pragma unroll 8
      for (int s = 0; s < SS; ++s) c += aw[s] * (float)eo_l[s*512 + q*64 + tid];
      _Float16* cr = comb + ((size_t)b*79 + trow)*1024;
      cr[q*64 + tid]       = hatt[q*64 + tid];
      cr[512 + q*64 + tid] = (_Float16)c;
    }
    __syncthreads();
  };

  // init: h(-1) = 0 in LDS (global slots zeroed by prep_all)
  if (tid < 128) *(u64*)&hbuf[tid*4] = 0ull;
  loadW(eWhh);
  float ebR=0.f, ebZ=0.f, ebN=0.f, dbR=0.f, dbZ=0.f, dbN=0.f;
  if (tid < 64) {
    ebR = ebhh[j]; ebZ = ebhh[512+j]; ebN = ebhh[1024+j];
    dbR = dbhh[j]; dbZ = dbhh[512+j]; dbN = dbhh[1024+j];
  }
  __syncthreads();

  // -------- encoder: k = 0..79 --------
  for (int k = 0; k < SS; ++k) {
    float gr_=0.f, gz_=0.f, gn_=0.f;
    if (tid < 64) {
      const float* gi = giE + ((size_t)b*SS + k)*1536;
      gr_ = gi[j]; gz_ = gi[512+j]; gn_ = gi[1024+j];   // prefetch pre-poll
    }
    consume(k & 1, (u64)(k & 15));
    if (k > 0 && tid < 128)                              // stash h(k-1)
      *(u64*)&eo_l[(k-1)*512 + tid*4] = *(const u64*)&hbuf[tid*4];
    gru(gr_, gz_, gn_, ebR, ebZ, ebN);
    publish((k+1) & 1, (u64)((k+1) & 15));
  }

  loadW(dWhh);   // per-thread regs, no sync needed

  // -------- decoder: k = 80..158 (t = k-80) --------
  for (int t = 0; t < TT-1; ++t) {
    const int k = 80 + t;
    float gr_=0.f, gz_=0.f, gn_=0.f;
    if (tid < 64) {
      const float* gi = giD + ((size_t)b*79 + t)*1536;
      gr_ = gi[j]; gz_ = gi[512+j]; gn_ = gi[1024+j];
    }
    consume(k & 1, (u64)(k & 15));
    if (tid < 128) {
      if (t == 0) *(u64*)&eo_l[79*512 + tid*4] = *(const u64*)&hbuf[tid*4];
      else        *(u64*)&hatt[tid*4]          = *(const u64*)&hbuf[tid*4];
    }
    gru(gr_, gz_, gn_, dbR, dbZ, dbN);
    publish((k+1) & 1, (u64)((k+1) & 15));
    if (t > 0) attention(t-1);                           // off the publish path
  }

  // final: h(158) in slot 1, tag 15 (own quarter already in hbuf)
  if (tid < 112) {
    const int m = tid + (tid >= q*16 ? 16 : 0);
    const u64* sp = hx + (size_t)4096 + b*128 + m;
    u64 v;
    int fast = 64;
    for (;;) {
      v = ld_sc0(sp);
      if ((v >> 60) == 15ull) break;
      if (--fast == 0) {
        v = aload(sp);
        int guard = 0;
        while ((v >> 60) != 15ull && guard < (1<<22)) { v = aload(sp); ++guard; }
        break;
      }
    }
    *(u64*)&hbuf[m*4] = unpack_word4(v);
  }
  __syncthreads();
  if (tid < 128) *(u64*)&hatt[tid*4] = *(const u64*)&hbuf[tid*4];
  __syncthreads();
  attention(TT-2);
}

extern "C" void kernel_launch(void* const* d_in, const int* in_sizes, int n_in,
                              void* d_out, int out_size, void* d_ws, size_t ws_size,
                              hipStream_t stream) {
  (void)in_sizes; (void)n_in; (void)out_size; (void)ws_size;
  const int*   src  = (const int*)d_in[0];
  const int*   tgt  = (const int*)d_in[1];
  const float* emb  = (const float*)d_in[2];
  const float* eWih = (const float*)d_in[3];
  const float* eWhh = (const float*)d_in[4];
  const float* ebih = (const float*)d_in[5];
  const float* ebhh = (const float*)d_in[6];
  const float* dWih = (const float*)d_in[7];
  const float* dWhh = (const float*)d_in[8];
  const float* dbih = (const float*)d_in[9];
  const float* dbhh = (const float*)d_in[10];
  const float* outW = (const float*)d_in[11];
  const float* outb = (const float*)d_in[12];
  float* out = (float*)d_out;

  char* p = (char*)d_ws;
  auto alloc = [&](size_t n){ char* r = p; p += (n + 255) & ~(size_t)255; return r; };
  _Float16* oWh  = (_Float16*)alloc((size_t)VV*1024*2);
  float*    giE  = (float*)alloc((size_t)2560*1536*4);
  float*    giD  = (float*)alloc((size_t)2560*1536*4);
  u64*      hx   = (u64*)alloc((size_t)2*32*128*8);
  _Float16* comb = (_Float16*)alloc((size_t)2560*1024*2);

  prep_all<<<996, 256, 0, stream>>>(src, tgt, emb, eWih, ebih, dWih, dbih,
                                    outW, oWh, giE, giD, hx);
  hipFuncSetAttribute((const void*)seq_pb,
                      hipFuncAttributeMaxDynamicSharedMemorySize, SEQ_SMEM);
  seq_pb<<<256, 512, SEQ_SMEM, stream>>>(eWhh, dWhh, ebhh, dbhh, giE, giD,
                                         hx, comb);
  logits_gemm<<<5120, 256, 0, stream>>>(comb, oWh, outb, out);
}

// Round 19
// 967.460 us; speedup vs baseline: 1.7847x; 1.7847x over previous
//
#include <hip/hip_runtime.h>

#define VV 32000
#define EE 256
#define HH 512
#define BB 32
#define SS 80
#define TT 80
// decoder rows = B*(T-1) = 2528, padded to 2560 (20 tiles of 128)

typedef __attribute__((ext_vector_type(8))) _Float16 half8;
typedef __attribute__((ext_vector_type(4))) _Float16 half4;
typedef __attribute__((ext_vector_type(4))) float floatx4;
typedef unsigned long long u64;

__device__ __forceinline__ void gload16(const _Float16* g, _Float16* l) {
  __builtin_amdgcn_global_load_lds((const __attribute__((address_space(1))) void*)g,
                                   (__attribute__((address_space(3))) void*)l, 16, 0, 0);
}

__device__ __forceinline__ u64 aload(const u64* p) {
  return __hip_atomic_load(p, __ATOMIC_RELAXED, __HIP_MEMORY_SCOPE_AGENT);
}
__device__ __forceinline__ void astore(u64* p, u64 v) {
  __hip_atomic_store(p, v, __ATOMIC_RELAXED, __HIP_MEMORY_SCOPE_AGENT);
}

// ---- 15-bit packing (r9-proven): |h|<=1 so fp16 bit14 (exp MSB) is 0 -------
__device__ __forceinline__ unsigned pack15(unsigned short u) {
  return (u & 0x3FFFu) | ((u >> 1) & 0x4000u);
}
__device__ __forceinline__ unsigned short unpack15(unsigned v) {
  return (unsigned short)((v & 0x3FFFu) | ((v & 0x4000u) << 1));
}
__device__ __forceinline__ u64 unpack_word4(u64 a) {  // -> 4 fp16 in a u64
  u64 o = 0;
#pragma unroll
  for (int i = 0; i < 4; ++i)
    o |= (u64)unpack15((unsigned)(a >> (15*i)) & 0x7FFFu) << (16*i);
  return o;
}

__device__ __forceinline__ float dot8(half8 a, half8 b, float c) {
  typedef __attribute__((ext_vector_type(2))) _Float16 half2v;
  half2v a0 = {a[0],a[1]}, a1 = {a[2],a[3]}, a2 = {a[4],a[5]}, a3 = {a[6],a[7]};
  half2v b0 = {b[0],b[1]}, b1 = {b[2],b[3]}, b2 = {b[4],b[5]}, b3 = {b[6],b[7]};
  c = __builtin_amdgcn_fdot2(a0, b0, c, false);
  c = __builtin_amdgcn_fdot2(a1, b1, c, false);
  c = __builtin_amdgcn_fdot2(a2, b2, c, false);
  c = __builtin_amdgcn_fdot2(a3, b3, c, false);
  return c;
}

__device__ __forceinline__ float sigm(float x) { return 1.f/(1.f + __expf(-x)); }
__device__ __forceinline__ float tanh_f(float x) { return 2.f/(1.f + __expf(-2.f*x)) - 1.f; }

// ---------------- prep: gi GEMMs (E+D) + oWh conversion in ONE launch --------
// blocks 0..479: gi GEMM (p%24<12 -> encoder, else decoder), r16-proven path.
// blocks 480..991: outW fp32 -> fp16 elementwise (independent; fills idle CUs).
__global__ __launch_bounds__(256) void prep_all(
    const int* __restrict__ src, const int* __restrict__ tgt,
    const float* __restrict__ emb,
    const float* __restrict__ eWih, const float* __restrict__ ebih,
    const float* __restrict__ dWih, const float* __restrict__ dbih,
    const float* __restrict__ outW, _Float16* __restrict__ oWh,
    float* __restrict__ giE, float* __restrict__ giD)
{
  const int pblk = blockIdx.x;
  const int tid = threadIdx.x;

  if (pblk >= 480) {                 // ---- oWh conversion path ----
    const int pid = pblk - 480;      // 0..511
    const long total8 = (long)VV*1024/8;
    for (long i = (long)pid*256 + tid; i < total8; i += 512L*256) {
      const float* s_ = outW + i*8;
      const floatx4 a = *(const floatx4*)s_;
      const floatx4 b = *(const floatx4*)(s_ + 4);
      half8 h;
      h[0]=(_Float16)a[0]; h[1]=(_Float16)a[1]; h[2]=(_Float16)a[2]; h[3]=(_Float16)a[3];
      h[4]=(_Float16)b[0]; h[5]=(_Float16)b[1]; h[6]=(_Float16)b[2]; h[7]=(_Float16)b[3];
      *(half8*)(oWh + i*8) = h;
    }
    return;
  }

  // ---- gi GEMM path (r16-proven) ----
  __shared__ _Float16 As[4096];
  __shared__ _Float16 Bs[4096];
  const int lane = tid & 63;
  const int wv = tid >> 6;
  const int wr = wv >> 1, wc = wv & 1;
  const int mt = pblk / 24;
  const int ntx = pblk % 24;
  const bool isE = ntx < 12;
  const int nt = isE ? ntx : ntx - 12;
  const float* Wih = isE ? eWih : dWih;
  const float* bih = isE ? ebih : dbih;
  float* gi = isE ? giE : giD;
  floatx4 acc[4][4];
#pragma unroll
  for (int i=0;i<4;++i)
#pragma unroll
    for (int j=0;j<4;++j) acc[i][j] = (floatx4){0.f,0.f,0.f,0.f};
  const int r2 = tid >> 1, cb = (tid & 1) * 16;
  const int R = mt*128 + r2;
  int tok = -1;
  if (isE) tok = src[R];
  else if (R < 2528) { const int b_ = R/79, tt = R - b_*79; tok = tgt[b_*80 + tt]; }
  const float* arow = (tok >= 0) ? emb + (size_t)tok*EE : nullptr;
  const float* brow = Wih + (size_t)(nt*128 + r2)*EE;
  const int g8 = (lane >> 4) * 8;
  const int lr = lane & 15;
  for (int kb = 0; kb < EE; kb += 32) {
    __syncthreads();
    if (arow) {
#pragma unroll
      for (int q = 0; q < 4; ++q) {
        const floatx4 va = *(const floatx4*)(arow + kb + cb + q*4);
#pragma unroll
        for (int e = 0; e < 4; ++e) As[r2*32 + cb + q*4 + e] = (_Float16)va[e];
      }
    } else {
#pragma unroll
      for (int q = 0; q < 16; ++q) As[r2*32 + cb + q] = (_Float16)0.f;
    }
#pragma unroll
    for (int q = 0; q < 4; ++q) {
      const floatx4 vb = *(const floatx4*)(brow + kb + cb + q*4);
#pragma unroll
      for (int e = 0; e < 4; ++e) Bs[r2*32 + cb + q*4 + e] = (_Float16)vb[e];
    }
    __syncthreads();
    half8 af[4], bf[4];
#pragma unroll
    for (int i=0;i<4;++i) af[i] = *(const half8*)(As + (wr*64 + i*16 + lr)*32 + g8);
#pragma unroll
    for (int j=0;j<4;++j) bf[j] = *(const half8*)(Bs + (wc*64 + j*16 + lr)*32 + g8);
#pragma unroll
    for (int i=0;i<4;++i)
#pragma unroll
      for (int j=0;j<4;++j)
        acc[i][j] = __builtin_amdgcn_mfma_f32_16x16x32_f16(af[i], bf[j], acc[i][j], 0,0,0);
  }
  const int rm = 4*(lane>>4);
#pragma unroll
  for (int i=0;i<4;++i)
#pragma unroll
    for (int r=0;r<4;++r) {
      const int row = mt*128 + wr*64 + i*16 + rm + r;
      if (isE || row < 2528) {
#pragma unroll
        for (int j=0;j<4;++j) {
          const int col = nt*128 + wc*64 + j*16 + lr;
          gi[(size_t)row*1536 + col] = acc[i][j][r] + bih[col];
        }
      }
    }
}

// ---------------- logits GEMM, XCD-clustered (EXACT r12/r15; proven) ---------
__global__ __launch_bounds__(256) void logits_gemm(
    const _Float16* __restrict__ A, const _Float16* __restrict__ Bm,
    const float* __restrict__ bias, float* __restrict__ out)
{
  const int p = blockIdx.x;
  const int x = p & 7, s = p >> 3;
  const int nt = x + 8*(s / 20);
  const int mt = s % 20;
  if (nt >= 250) return;
  __shared__ _Float16 As[4096];
  __shared__ _Float16 Bs[4096];
  const int tid = threadIdx.x;
  const int lane = tid & 63;
  const int wv = tid >> 6;
  const int wr = wv >> 1, wc = wv & 1;
  floatx4 acc[4][4];
#pragma unroll
  for (int i=0;i<4;++i)
#pragma unroll
    for (int j=0;j<4;++j) acc[i][j] = (floatx4){0.f,0.f,0.f,0.f};
  const int srow = lane >> 2;
  const int scol = (lane & 3) * 8;
  const _Float16* Ab = A + (size_t)(mt*128)*1024;
  const _Float16* Bb = Bm + (size_t)(nt*128)*1024;
  const int g8 = (lane >> 4) * 8;
  const int lr = lane & 15;
  for (int kb = 0; kb < 1024; kb += 32) {
    __syncthreads();
#pragma unroll
    for (int cc = 0; cc < 2; ++cc) {
      const int c = wv*2 + cc;
      gload16(Ab + (size_t)(c*16 + srow)*1024 + kb + scol, As + c*512);
      gload16(Bb + (size_t)(c*16 + srow)*1024 + kb + scol, Bs + c*512);
    }
    __syncthreads();
    half8 af[4], bf[4];
#pragma unroll
    for (int i=0;i<4;++i) af[i] = *(const half8*)(As + (wr*64 + i*16 + lr)*32 + g8);
#pragma unroll
    for (int j=0;j<4;++j) bf[j] = *(const half8*)(Bs + (wc*64 + j*16 + lr)*32 + g8);
#pragma unroll
    for (int i=0;i<4;++i)
#pragma unroll
      for (int j=0;j<4;++j)
        acc[i][j] = __builtin_amdgcn_mfma_f32_16x16x32_f16(af[i], bf[j], acc[i][j], 0,0,0);
  }
  const int rm = 4*(lane>>4);
#pragma unroll
  for (int i=0;i<4;++i)
#pragma unroll
    for (int r=0;r<4;++r) {
      const int row = mt*128 + wr*64 + i*16 + rm + r;
#pragma unroll
      for (int j=0;j<4;++j) {
        const int col = nt*128 + wc*64 + j*16 + lr;
        if (row < 2528) {
          const int b = row / 79;
          const int t = row - b*79;
          out[(size_t)(b*80 + t + 1)*VV + col] = acc[i][j][r] + bias[col];
        } else {
          out[(size_t)((row - 2528)*80)*VV + col] = 0.f;
        }
      }
    }
}

// ---------------- per-batch decoupled recurrence (EXACT r15/r17; 648us) ------
// 256 WGs x 512 thr; blockIdx = q*32 + b (8 WGs per batch, q=0..7).
// WG (b,q) owns output cols [q*64, q*64+64); Whh slice in REGISTERS.
// Exchange only within the batch's 8 WGs (r9 tag-in-data, 15-bit pack +
// 4-bit tag; slot k&1 / (k+1)&1; memset-0 = valid h(-1) + non-matching tag).
// Attention split across the batch's 8 WGs, off the publish path.
#define SEQ_SMEM (80*512*2 + 512*2 + 512*2 + 3*64*8*4 + 2*80*4)
__global__ __launch_bounds__(512) void seq_pb(
    const float* __restrict__ eWhh, const float* __restrict__ dWhh,
    const float* __restrict__ ebhh, const float* __restrict__ dbhh,
    const float* __restrict__ giE, const float* __restrict__ giD,
    u64* __restrict__ hx,          // [2][32][128] u64, memset 0
    _Float16* __restrict__ comb)
{
  extern __shared__ char smem[];
  _Float16* eo_l = (_Float16*)smem;          // [80][512]
  _Float16* hbuf = eo_l + 80*512;            // [512]
  _Float16* hatt = hbuf + 512;               // [512]
  float* part = (float*)(hatt + 512);        // [3][64][8]
  float* sc = part + 3*64*8;                 // [80]
  float* aw = sc + 80;                       // [80]

  const int bi = blockIdx.x;
  const int q = bi >> 5, b = bi & 31;
  const int tid = threadIdx.x;
  const int lane = tid & 63;
  const int wv = tid >> 6;
  const int jl = tid & 63;        // local col
  const int kq = tid >> 6;        // k-chunk 0..7
  const int j  = q*64 + jl;       // global col

  half8 wreg[3][8];               // register-resident weights
  auto loadW = [&](const float* W){
#pragma unroll
    for (int g = 0; g < 3; ++g)
#pragma unroll
      for (int c = 0; c < 8; ++c) {
        const float* s8 = W + ((size_t)(g*512 + j))*512 + kq*64 + c*8;
        const floatx4 a = *(const floatx4*)s8;
        const floatx4 d = *(const floatx4*)(s8 + 4);
        half8 h;
        h[0]=(_Float16)a[0]; h[1]=(_Float16)a[1]; h[2]=(_Float16)a[2]; h[3]=(_Float16)a[3];
        h[4]=(_Float16)d[0]; h[5]=(_Float16)d[1]; h[6]=(_Float16)d[2]; h[7]=(_Float16)d[3];
        wreg[g][c] = h;
      }
  };

  auto consume = [&](int slotR, u64 rtag){
    if (tid < 112) {               // 112 partner words; own 16 words stay local
      const int m = tid + (tid >= q*16 ? 16 : 0);
      const u64* sp = hx + (size_t)slotR*4096 + b*128 + m;
      u64 v = aload(sp);
      int guard = 0;
      while ((v >> 60) != rtag && guard < (1<<22)) { v = aload(sp); ++guard; }
      *(u64*)&hbuf[m*4] = unpack_word4(v);
    }
    __syncthreads();
  };
  auto publish = [&](int slotW, u64 wtag){
    if (tid < 16) {
      const int m = q*16 + tid;
      u64 wq = wtag << 60;
#pragma unroll
      for (int e = 0; e < 4; ++e) {
        union { _Float16 h; unsigned short u; } cv; cv.h = hbuf[m*4 + e];
        wq |= (u64)pack15(cv.u) << (15*e);
      }
      astore(hx + (size_t)slotW*4096 + b*128 + m, wq);
    }
  };

  float hp = 0.f;                 // fp32 h_prev for col j (tid<64 only)
  auto gru = [&](float gr_, float gz_, float gn_, float bR, float bZ, float bN){
    half8 hv[8];
#pragma unroll
    for (int c = 0; c < 8; ++c) hv[c] = *(const half8*)&hbuf[kq*64 + c*8];
    float p0 = 0.f, p1 = 0.f, p2 = 0.f;
#pragma unroll
    for (int c = 0; c < 8; ++c) {
      p0 = dot8(wreg[0][c], hv[c], p0);
      p1 = dot8(wreg[1][c], hv[c], p1);
      p2 = dot8(wreg[2][c], hv[c], p2);
    }
    part[(0*64 + jl)*8 + kq] = p0;
    part[(1*64 + jl)*8 + kq] = p1;
    part[(2*64 + jl)*8 + kq] = p2;
    __syncthreads();
    if (tid < 64) {
      float a0 = 0.f, a1 = 0.f, a2 = 0.f;
#pragma unroll
      for (int e = 0; e < 8; ++e) {
        a0 += part[(0*64 + tid)*8 + e];
        a1 += part[(1*64 + tid)*8 + e];
        a2 += part[(2*64 + tid)*8 + e];
      }
      const float rg = sigm(gr_ + a0 + bR);
      const float zg = sigm(gz_ + a1 + bZ);
      const float ng = tanh_f(gn_ + rg*(a2 + bN));
      const float hn = (1.f - zg)*ng + zg*hp;     // |hn| <= 1 by induction
      hp = hn;
      hbuf[q*64 + tid] = (_Float16)hn;
    }
    __syncthreads();
  };

  auto attention = [&](int trow){
    const half8 hf = *(const half8*)&hatt[lane*8];
#pragma unroll 2
    for (int i = 0; i < 10; ++i) {               // 8 waves x 10 scores
      const int s = wv*10 + i;
      const half8 ev = *(const half8*)&eo_l[s*512 + lane*8];
      float pt = dot8(ev, hf, 0.f);
#pragma unroll
      for (int o = 32; o; o >>= 1) pt += __shfl_xor(pt, o);
      if (lane == 0) sc[s] = pt;
    }
    __syncthreads();
    if (wv == 0) {                               // softmax over 80 (wave 0)
      const float v0 = sc[lane];
      const float v1 = (lane < 16) ? sc[64+lane] : -1e30f;
      float m = fmaxf(v0, v1);
#pragma unroll
      for (int o = 32; o; o >>= 1) m = fmaxf(m, __shfl_xor(m, o));
      const float e0 = __expf(v0 - m);
      const float e1 = (lane < 16) ? __expf(v1 - m) : 0.f;
      float ssum = e0 + e1;
#pragma unroll
      for (int o = 32; o; o >>= 1) ssum += __shfl_xor(ssum, o);
      const float inv = 1.f/ssum;
      aw[lane] = e0*inv;
      if (lane < 16) aw[64+lane] = e1*inv;
    }
    __syncthreads();
    if (tid < 64) {                              // own 64 ctx cols
      float c = 0.f;
#pragma unroll 8
      for (int s = 0; s < SS; ++s) c += aw[s] * (float)eo_l[s*512 + q*64 + tid];
      _Float16* cr = comb + ((size_t)b*79 + trow)*1024;
      cr[q*64 + tid]       = hatt[q*64 + tid];
      cr[512 + q*64 + tid] = (_Float16)c;
    }
    __syncthreads();
  };

  // init: h(-1) = 0 in LDS (global slots pre-memset 0)
  if (tid < 128) *(u64*)&hbuf[tid*4] = 0ull;
  loadW(eWhh);
  float ebR=0.f, ebZ=0.f, ebN=0.f, dbR=0.f, dbZ=0.f, dbN=0.f;
  if (tid < 64) {
    ebR = ebhh[j]; ebZ = ebhh[512+j]; ebN = ebhh[1024+j];
    dbR = dbhh[j]; dbZ = dbhh[512+j]; dbN = dbhh[1024+j];
  }
  __syncthreads();

  // -------- encoder: k = 0..79 --------
  for (int k = 0; k < SS; ++k) {
    float gr_=0.f, gz_=0.f, gn_=0.f;
    if (tid < 64) {
      const float* gi = giE + ((size_t)b*SS + k)*1536;
      gr_ = gi[j]; gz_ = gi[512+j]; gn_ = gi[1024+j];   // prefetch pre-poll
    }
    consume(k & 1, (u64)(k & 15));
    if (k > 0 && tid < 128)                              // stash h(k-1)
      *(u64*)&eo_l[(k-1)*512 + tid*4] = *(const u64*)&hbuf[tid*4];
    gru(gr_, gz_, gn_, ebR, ebZ, ebN);
    publish((k+1) & 1, (u64)((k+1) & 15));
  }

  loadW(dWhh);   // per-thread regs, no sync needed

  // -------- decoder: k = 80..158 (t = k-80) --------
  for (int t = 0; t < TT-1; ++t) {
    const int k = 80 + t;
    float gr_=0.f, gz_=0.f, gn_=0.f;
    if (tid < 64) {
      const float* gi = giD + ((size_t)b*79 + t)*1536;
      gr_ = gi[j]; gz_ = gi[512+j]; gn_ = gi[1024+j];
    }
    consume(k & 1, (u64)(k & 15));
    if (tid < 128) {
      if (t == 0) *(u64*)&eo_l[79*512 + tid*4] = *(const u64*)&hbuf[tid*4];
      else        *(u64*)&hatt[tid*4]          = *(const u64*)&hbuf[tid*4];
    }
    gru(gr_, gz_, gn_, dbR, dbZ, dbN);
    publish((k+1) & 1, (u64)((k+1) & 15));
    if (t > 0) attention(t-1);                           // off the publish path
  }

  // final: h(158) in slot 1, tag 15 (own quarter already in hbuf)
  if (tid < 112) {
    const int m = tid + (tid >= q*16 ? 16 : 0);
    const u64* sp = hx + (size_t)4096 + b*128 + m;
    u64 v = aload(sp);
    int guard = 0;
    while ((v >> 60) != 15ull && guard < (1<<22)) { v = aload(sp); ++guard; }
    *(u64*)&hbuf[m*4] = unpack_word4(v);
  }
  __syncthreads();
  if (tid < 128) *(u64*)&hatt[tid*4] = *(const u64*)&hbuf[tid*4];
  __syncthreads();
  attention(TT-2);
}

extern "C" void kernel_launch(void* const* d_in, const int* in_sizes, int n_in,
                              void* d_out, int out_size, void* d_ws, size_t ws_size,
                              hipStream_t stream) {
  (void)in_sizes; (void)n_in; (void)out_size; (void)ws_size;
  const int*   src  = (const int*)d_in[0];
  const int*   tgt  = (const int*)d_in[1];
  const float* emb  = (const float*)d_in[2];
  const float* eWih = (const float*)d_in[3];
  const float* eWhh = (const float*)d_in[4];
  const float* ebih = (const float*)d_in[5];
  const float* ebhh = (const float*)d_in[6];
  const float* dWih = (const float*)d_in[7];
  const float* dWhh = (const float*)d_in[8];
  const float* dbih = (const float*)d_in[9];
  const float* dbhh = (const float*)d_in[10];
  const float* outW = (const float*)d_in[11];
  const float* outb = (const float*)d_in[12];
  float* out = (float*)d_out;

  char* p = (char*)d_ws;
  auto alloc = [&](size_t n){ char* r = p; p += (n + 255) & ~(size_t)255; return r; };
  _Float16* oWh  = (_Float16*)alloc((size_t)VV*1024*2);
  float*    giE  = (float*)alloc((size_t)2560*1536*4);
  float*    giD  = (float*)alloc((size_t)2560*1536*4);
  u64*      hx   = (u64*)alloc((size_t)2*32*128*8);
  _Float16* comb = (_Float16*)alloc((size_t)2560*1024*2);

  hipMemsetAsync(hx, 0, (size_t)2*32*128*8, stream);   // slots+tags = 0
  prep_all<<<992, 256, 0, stream>>>(src, tgt, emb, eWih, ebih, dWih, dbih,
                                    outW, oWh, giE, giD);
  hipFuncSetAttribute((const void*)seq_pb,
                      hipFuncAttributeMaxDynamicSharedMemorySize, SEQ_SMEM);
  seq_pb<<<256, 512, SEQ_SMEM, stream>>>(eWhh, dWhh, ebhh, dbhh, giE, giD,
                                         hx, comb);
  logits_gemm<<<5120, 256, 0, stream>>>(comb, oWh, outb, out);
}

// Round 20
// 964.222 us; speedup vs baseline: 1.7907x; 1.0034x over previous
//
#include <hip/hip_runtime.h>

#define VV 32000
#define EE 256
#define HH 512
#define BB 32
#define SS 80
#define TT 80
// decoder rows = B*(T-1) = 2528, padded to 2560 (20 tiles of 128)

typedef __attribute__((ext_vector_type(8))) _Float16 half8;
typedef __attribute__((ext_vector_type(4))) _Float16 half4;
typedef __attribute__((ext_vector_type(4))) float floatx4;
typedef unsigned long long u64;

__device__ __forceinline__ void gload16(const _Float16* g, _Float16* l) {
  __builtin_amdgcn_global_load_lds((const __attribute__((address_space(1))) void*)g,
                                   (__attribute__((address_space(3))) void*)l, 16, 0, 0);
}

__device__ __forceinline__ u64 aload(const u64* p) {
  return __hip_atomic_load(p, __ATOMIC_RELAXED, __HIP_MEMORY_SCOPE_AGENT);
}
__device__ __forceinline__ void astore(u64* p, u64 v) {
  __hip_atomic_store(p, v, __ATOMIC_RELAXED, __HIP_MEMORY_SCOPE_AGENT);
}

// ---- 15-bit packing (r9-proven): |h|<=1 so fp16 bit14 (exp MSB) is 0 -------
__device__ __forceinline__ unsigned pack15(unsigned short u) {
  return (u & 0x3FFFu) | ((u >> 1) & 0x4000u);
}
__device__ __forceinline__ unsigned short unpack15(unsigned v) {
  return (unsigned short)((v & 0x3FFFu) | ((v & 0x4000u) << 1));
}
__device__ __forceinline__ u64 unpack_word4(u64 a) {  // -> 4 fp16 in a u64
  u64 o = 0;
#pragma unroll
  for (int i = 0; i < 4; ++i)
    o |= (u64)unpack15((unsigned)(a >> (15*i)) & 0x7FFFu) << (16*i);
  return o;
}

__device__ __forceinline__ float dot8(half8 a, half8 b, float c) {
  typedef __attribute__((ext_vector_type(2))) _Float16 half2v;
  half2v a0 = {a[0],a[1]}, a1 = {a[2],a[3]}, a2 = {a[4],a[5]}, a3 = {a[6],a[7]};
  half2v b0 = {b[0],b[1]}, b1 = {b[2],b[3]}, b2 = {b[4],b[5]}, b3 = {b[6],b[7]};
  c = __builtin_amdgcn_fdot2(a0, b0, c, false);
  c = __builtin_amdgcn_fdot2(a1, b1, c, false);
  c = __builtin_amdgcn_fdot2(a2, b2, c, false);
  c = __builtin_amdgcn_fdot2(a3, b3, c, false);
  return c;
}

__device__ __forceinline__ float sigm(float x) { return 1.f/(1.f + __expf(-x)); }
__device__ __forceinline__ float tanh_f(float x) { return 2.f/(1.f + __expf(-2.f*x)) - 1.f; }

// ---------------- prep: gi GEMMs + oWh conversion + hx init, ONE launch ------
// blocks 0..479: gi GEMM (p%24<12 -> encoder, else decoder), r16-proven path.
// blocks 480..991: outW fp32 -> fp16 elementwise.
// blocks 992..995: zero hx (sc1; r18-proven fold -- completes before seq_pb).
__global__ __launch_bounds__(256) void prep_all(
    const int* __restrict__ src, const int* __restrict__ tgt,
    const float* __restrict__ emb,
    const float* __restrict__ eWih, const float* __restrict__ ebih,
    const float* __restrict__ dWih, const float* __restrict__ dbih,
    const float* __restrict__ outW, _Float16* __restrict__ oWh,
    float* __restrict__ giE, float* __restrict__ giD,
    u64* __restrict__ hx)
{
  const int pblk = blockIdx.x;
  const int tid = threadIdx.x;

  if (pblk >= 992) {                 // ---- hx zero-init (8192 u64 words) ----
    const int pid = pblk - 992;      // 0..3
    for (int i = pid*256 + tid; i < 8192; i += 4*256) astore(hx + i, 0ull);
    return;
  }
  if (pblk >= 480) {                 // ---- oWh conversion path ----
    const int pid = pblk - 480;      // 0..511
    const long total8 = (long)VV*1024/8;
    for (long i = (long)pid*256 + tid; i < total8; i += 512L*256) {
      const float* s_ = outW + i*8;
      const floatx4 a = *(const floatx4*)s_;
      const floatx4 b = *(const floatx4*)(s_ + 4);
      half8 h;
      h[0]=(_Float16)a[0]; h[1]=(_Float16)a[1]; h[2]=(_Float16)a[2]; h[3]=(_Float16)a[3];
      h[4]=(_Float16)b[0]; h[5]=(_Float16)b[1]; h[6]=(_Float16)b[2]; h[7]=(_Float16)b[3];
      *(half8*)(oWh + i*8) = h;
    }
    return;
  }

  // ---- gi GEMM path (r16-proven) ----
  __shared__ _Float16 As[4096];
  __shared__ _Float16 Bs[4096];
  const int lane = tid & 63;
  const int wv = tid >> 6;
  const int wr = wv >> 1, wc = wv & 1;
  const int mt = pblk / 24;
  const int ntx = pblk % 24;
  const bool isE = ntx < 12;
  const int nt = isE ? ntx : ntx - 12;
  const float* Wih = isE ? eWih : dWih;
  const float* bih = isE ? ebih : dbih;
  float* gi = isE ? giE : giD;
  floatx4 acc[4][4];
#pragma unroll
  for (int i=0;i<4;++i)
#pragma unroll
    for (int j=0;j<4;++j) acc[i][j] = (floatx4){0.f,0.f,0.f,0.f};
  const int r2 = tid >> 1, cb = (tid & 1) * 16;
  const int R = mt*128 + r2;
  int tok = -1;
  if (isE) tok = src[R];
  else if (R < 2528) { const int b_ = R/79, tt = R - b_*79; tok = tgt[b_*80 + tt]; }
  const float* arow = (tok >= 0) ? emb + (size_t)tok*EE : nullptr;
  const float* brow = Wih + (size_t)(nt*128 + r2)*EE;
  const int g8 = (lane >> 4) * 8;
  const int lr = lane & 15;
  for (int kb = 0; kb < EE; kb += 32) {
    __syncthreads();
    if (arow) {
#pragma unroll
      for (int q = 0; q < 4; ++q) {
        const floatx4 va = *(const floatx4*)(arow + kb + cb + q*4);
#pragma unroll
        for (int e = 0; e < 4; ++e) As[r2*32 + cb + q*4 + e] = (_Float16)va[e];
      }
    } else {
#pragma unroll
      for (int q = 0; q < 16; ++q) As[r2*32 + cb + q] = (_Float16)0.f;
    }
#pragma unroll
    for (int q = 0; q < 4; ++q) {
      const floatx4 vb = *(const floatx4*)(brow + kb + cb + q*4);
#pragma unroll
      for (int e = 0; e < 4; ++e) Bs[r2*32 + cb + q*4 + e] = (_Float16)vb[e];
    }
    __syncthreads();
    half8 af[4], bf[4];
#pragma unroll
    for (int i=0;i<4;++i) af[i] = *(const half8*)(As + (wr*64 + i*16 + lr)*32 + g8);
#pragma unroll
    for (int j=0;j<4;++j) bf[j] = *(const half8*)(Bs + (wc*64 + j*16 + lr)*32 + g8);
#pragma unroll
    for (int i=0;i<4;++i)
#pragma unroll
      for (int j=0;j<4;++j)
        acc[i][j] = __builtin_amdgcn_mfma_f32_16x16x32_f16(af[i], bf[j], acc[i][j], 0,0,0);
  }
  const int rm = 4*(lane>>4);
#pragma unroll
  for (int i=0;i<4;++i)
#pragma unroll
    for (int r=0;r<4;++r) {
      const int row = mt*128 + wr*64 + i*16 + rm + r;
      if (isE || row < 2528) {
#pragma unroll
        for (int j=0;j<4;++j) {
          const int col = nt*128 + wc*64 + j*16 + lr;
          gi[(size_t)row*1536 + col] = acc[i][j][r] + bih[col];
        }
      }
    }
}

// ---------------- logits GEMM, XCD-clustered (EXACT r12/r15; proven) ---------
__global__ __launch_bounds__(256) void logits_gemm(
    const _Float16* __restrict__ A, const _Float16* __restrict__ Bm,
    const float* __restrict__ bias, float* __restrict__ out)
{
  const int p = blockIdx.x;
  const int x = p & 7, s = p >> 3;
  const int nt = x + 8*(s / 20);
  const int mt = s % 20;
  if (nt >= 250) return;
  __shared__ _Float16 As[4096];
  __shared__ _Float16 Bs[4096];
  const int tid = threadIdx.x;
  const int lane = tid & 63;
  const int wv = tid >> 6;
  const int wr = wv >> 1, wc = wv & 1;
  floatx4 acc[4][4];
#pragma unroll
  for (int i=0;i<4;++i)
#pragma unroll
    for (int j=0;j<4;++j) acc[i][j] = (floatx4){0.f,0.f,0.f,0.f};
  const int srow = lane >> 2;
  const int scol = (lane & 3) * 8;
  const _Float16* Ab = A + (size_t)(mt*128)*1024;
  const _Float16* Bb = Bm + (size_t)(nt*128)*1024;
  const int g8 = (lane >> 4) * 8;
  const int lr = lane & 15;
  for (int kb = 0; kb < 1024; kb += 32) {
    __syncthreads();
#pragma unroll
    for (int cc = 0; cc < 2; ++cc) {
      const int c = wv*2 + cc;
      gload16(Ab + (size_t)(c*16 + srow)*1024 + kb + scol, As + c*512);
      gload16(Bb + (size_t)(c*16 + srow)*1024 + kb + scol, Bs + c*512);
    }
    __syncthreads();
    half8 af[4], bf[4];
#pragma unroll
    for (int i=0;i<4;++i) af[i] = *(const half8*)(As + (wr*64 + i*16 + lr)*32 + g8);
#pragma unroll
    for (int j=0;j<4;++j) bf[j] = *(const half8*)(Bs + (wc*64 + j*16 + lr)*32 + g8);
#pragma unroll
    for (int i=0;i<4;++i)
#pragma unroll
      for (int j=0;j<4;++j)
        acc[i][j] = __builtin_amdgcn_mfma_f32_16x16x32_f16(af[i], bf[j], acc[i][j], 0,0,0);
  }
  const int rm = 4*(lane>>4);
#pragma unroll
  for (int i=0;i<4;++i)
#pragma unroll
    for (int r=0;r<4;++r) {
      const int row = mt*128 + wr*64 + i*16 + rm + r;
#pragma unroll
      for (int j=0;j<4;++j) {
        const int col = nt*128 + wc*64 + j*16 + lr;
        if (row < 2528) {
          const int b = row / 79;
          const int t = row - b*79;
          out[(size_t)(b*80 + t + 1)*VV + col] = acc[i][j][r] + bias[col];
        } else {
          out[(size_t)((row - 2528)*80)*VV + col] = 0.f;
        }
      }
    }
}

// ---------------- per-batch decoupled recurrence (EXACT r15/r17; 648us) ------
// 256 WGs x 512 thr; blockIdx = q*32 + b (8 WGs per batch, q=0..7).
// WG (b,q) owns output cols [q*64, q*64+64); Whh slice in REGISTERS.
// Exchange only within the batch's 8 WGs (r9 tag-in-data, 15-bit pack +
// 4-bit tag; slot k&1 / (k+1)&1; zeroed hx = valid h(-1) + non-matching tag).
// Attention split across the batch's 8 WGs, off the publish path.
#define SEQ_SMEM (80*512*2 + 512*2 + 512*2 + 3*64*8*4 + 2*80*4)
__global__ __launch_bounds__(512) void seq_pb(
    const float* __restrict__ eWhh, const float* __restrict__ dWhh,
    const float* __restrict__ ebhh, const float* __restrict__ dbhh,
    const float* __restrict__ giE, const float* __restrict__ giD,
    u64* __restrict__ hx,          // [2][32][128] u64, zeroed by prep_all
    _Float16* __restrict__ comb)
{
  extern __shared__ char smem[];
  _Float16* eo_l = (_Float16*)smem;          // [80][512]
  _Float16* hbuf = eo_l + 80*512;            // [512]
  _Float16* hatt = hbuf + 512;               // [512]
  float* part = (float*)(hatt + 512);        // [3][64][8]
  float* sc = part + 3*64*8;                 // [80]
  float* aw = sc + 80;                       // [80]

  const int bi = blockIdx.x;
  const int q = bi >> 5, b = bi & 31;
  const int tid = threadIdx.x;
  const int lane = tid & 63;
  const int wv = tid >> 6;
  const int jl = tid & 63;        // local col
  const int kq = tid >> 6;        // k-chunk 0..7
  const int j  = q*64 + jl;       // global col

  half8 wreg[3][8];               // register-resident weights
  auto loadW = [&](const float* W){
#pragma unroll
    for (int g = 0; g < 3; ++g)
#pragma unroll
      for (int c = 0; c < 8; ++c) {
        const float* s8 = W + ((size_t)(g*512 + j))*512 + kq*64 + c*8;
        const floatx4 a = *(const floatx4*)s8;
        const floatx4 d = *(const floatx4*)(s8 + 4);
        half8 h;
        h[0]=(_Float16)a[0]; h[1]=(_Float16)a[1]; h[2]=(_Float16)a[2]; h[3]=(_Float16)a[3];
        h[4]=(_Float16)d[0]; h[5]=(_Float16)d[1]; h[6]=(_Float16)d[2]; h[7]=(_Float16)d[3];
        wreg[g][c] = h;
      }
  };

  auto consume = [&](int slotR, u64 rtag){
    if (tid < 112) {               // 112 partner words; own 16 words stay local
      const int m = tid + (tid >= q*16 ? 16 : 0);
      const u64* sp = hx + (size_t)slotR*4096 + b*128 + m;
      u64 v = aload(sp);
      int guard = 0;
      while ((v >> 60) != rtag && guard < (1<<22)) { v = aload(sp); ++guard; }
      *(u64*)&hbuf[m*4] = unpack_word4(v);
    }
    __syncthreads();
  };
  auto publish = [&](int slotW, u64 wtag){
    if (tid < 16) {
      const int m = q*16 + tid;
      u64 wq = wtag << 60;
#pragma unroll
      for (int e = 0; e < 4; ++e) {
        union { _Float16 h; unsigned short u; } cv; cv.h = hbuf[m*4 + e];
        wq |= (u64)pack15(cv.u) << (15*e);
      }
      astore(hx + (size_t)slotW*4096 + b*128 + m, wq);
    }
  };

  float hp = 0.f;                 // fp32 h_prev for col j (tid<64 only)
  auto gru = [&](float gr_, float gz_, float gn_, float bR, float bZ, float bN){
    half8 hv[8];
#pragma unroll
    for (int c = 0; c < 8; ++c) hv[c] = *(const half8*)&hbuf[kq*64 + c*8];
    float p0 = 0.f, p1 = 0.f, p2 = 0.f;
#pragma unroll
    for (int c = 0; c < 8; ++c) {
      p0 = dot8(wreg[0][c], hv[c], p0);
      p1 = dot8(wreg[1][c], hv[c], p1);
      p2 = dot8(wreg[2][c], hv[c], p2);
    }
    part[(0*64 + jl)*8 + kq] = p0;
    part[(1*64 + jl)*8 + kq] = p1;
    part[(2*64 + jl)*8 + kq] = p2;
    __syncthreads();
    if (tid < 64) {
      float a0 = 0.f, a1 = 0.f, a2 = 0.f;
#pragma unroll
      for (int e = 0; e < 8; ++e) {
        a0 += part[(0*64 + tid)*8 + e];
        a1 += part[(1*64 + tid)*8 + e];
        a2 += part[(2*64 + tid)*8 + e];
      }
      const float rg = sigm(gr_ + a0 + bR);
      const float zg = sigm(gz_ + a1 + bZ);
      const float ng = tanh_f(gn_ + rg*(a2 + bN));
      const float hn = (1.f - zg)*ng + zg*hp;     // |hn| <= 1 by induction
      hp = hn;
      hbuf[q*64 + tid] = (_Float16)hn;
    }
    __syncthreads();
  };

  auto attention = [&](int trow){
    const half8 hf = *(const half8*)&hatt[lane*8];
#pragma unroll 2
    for (int i = 0; i < 10; ++i) {               // 8 waves x 10 scores
      const int s = wv*10 + i;
      const half8 ev = *(const half8*)&eo_l[s*512 + lane*8];
      float pt = dot8(ev, hf, 0.f);
#pragma unroll
      for (int o = 32; o; o >>= 1) pt += __shfl_xor(pt, o);
      if (lane == 0) sc[s] = pt;
    }
    __syncthreads();
    if (wv == 0) {                               // softmax over 80 (wave 0)
      const float v0 = sc[lane];
      const float v1 = (lane < 16) ? sc[64+lane] : -1e30f;
      float m = fmaxf(v0, v1);
#pragma unroll
      for (int o = 32; o; o >>= 1) m = fmaxf(m, __shfl_xor(m, o));
      const float e0 = __expf(v0 - m);
      const float e1 = (lane < 16) ? __expf(v1 - m) : 0.f;
      float ssum = e0 + e1;
#pragma unroll
      for (int o = 32; o; o >>= 1) ssum += __shfl_xor(ssum, o);
      const float inv = 1.f/ssum;
      aw[lane] = e0*inv;
      if (lane < 16) aw[64+lane] = e1*inv;
    }
    __syncthreads();
    if (tid < 64) {                              // own 64 ctx cols
      float c = 0.f;
#pragma unroll 8
      for (int s = 0; s < SS; ++s) c += aw[s] * (float)eo_l[s*512 + q*64 + tid];
      _Float16* cr = comb + ((size_t)b*79 + trow)*1024;
      cr[q*64 + tid]       = hatt[q*64 + tid];
      cr[512 + q*64 + tid] = (_Float16)c;
    }
    __syncthreads();
  };

  // init: h(-1) = 0 in LDS (global slots zeroed by prep_all)
  if (tid < 128) *(u64*)&hbuf[tid*4] = 0ull;
  loadW(eWhh);
  float ebR=0.f, ebZ=0.f, ebN=0.f, dbR=0.f, dbZ=0.f, dbN=0.f;
  if (tid < 64) {
    ebR = ebhh[j]; ebZ = ebhh[512+j]; ebN = ebhh[1024+j];
    dbR = dbhh[j]; dbZ = dbhh[512+j]; dbN = dbhh[1024+j];
  }
  __syncthreads();

  // -------- encoder: k = 0..79 --------
  for (int k = 0; k < SS; ++k) {
    float gr_=0.f, gz_=0.f, gn_=0.f;
    if (tid < 64) {
      const float* gi = giE + ((size_t)b*SS + k)*1536;
      gr_ = gi[j]; gz_ = gi[512+j]; gn_ = gi[1024+j];   // prefetch pre-poll
    }
    consume(k & 1, (u64)(k & 15));
    if (k > 0 && tid < 128)                              // stash h(k-1)
      *(u64*)&eo_l[(k-1)*512 + tid*4] = *(const u64*)&hbuf[tid*4];
    gru(gr_, gz_, gn_, ebR, ebZ, ebN);
    publish((k+1) & 1, (u64)((k+1) & 15));
  }

  loadW(dWhh);   // per-thread regs, no sync needed

  // -------- decoder: k = 80..158 (t = k-80) --------
  for (int t = 0; t < TT-1; ++t) {
    const int k = 80 + t;
    float gr_=0.f, gz_=0.f, gn_=0.f;
    if (tid < 64) {
      const float* gi = giD + ((size_t)b*79 + t)*1536;
      gr_ = gi[j]; gz_ = gi[512+j]; gn_ = gi[1024+j];
    }
    consume(k & 1, (u64)(k & 15));
    if (tid < 128) {
      if (t == 0) *(u64*)&eo_l[79*512 + tid*4] = *(const u64*)&hbuf[tid*4];
      else        *(u64*)&hatt[tid*4]          = *(const u64*)&hbuf[tid*4];
    }
    gru(gr_, gz_, gn_, dbR, dbZ, dbN);
    publish((k+1) & 1, (u64)((k+1) & 15));
    if (t > 0) attention(t-1);                           // off the publish path
  }

  // final: h(158) in slot 1, tag 15 (own quarter already in hbuf)
  if (tid < 112) {
    const int m = tid + (tid >= q*16 ? 16 : 0);
    const u64* sp = hx + (size_t)4096 + b*128 + m;
    u64 v = aload(sp);
    int guard = 0;
    while ((v >> 60) != 15ull && guard < (1<<22)) { v = aload(sp); ++guard; }
    *(u64*)&hbuf[m*4] = unpack_word4(v);
  }
  __syncthreads();
  if (tid < 128) *(u64*)&hatt[tid*4] = *(const u64*)&hbuf[tid*4];
  __syncthreads();
  attention(TT-2);
}

extern "C" void kernel_launch(void* const* d_in, const int* in_sizes, int n_in,
                              void* d_out, int out_size, void* d_ws, size_t ws_size,
                              hipStream_t stream) {
  (void)in_sizes; (void)n_in; (void)out_size; (void)ws_size;
  const int*   src  = (const int*)d_in[0];
  const int*   tgt  = (const int*)d_in[1];
  const float* emb  = (const float*)d_in[2];
  const float* eWih = (const float*)d_in[3];
  const float* eWhh = (const float*)d_in[4];
  const float* ebih = (const float*)d_in[5];
  const float* ebhh = (const float*)d_in[6];
  const float* dWih = (const float*)d_in[7];
  const float* dWhh = (const float*)d_in[8];
  const float* dbih = (const float*)d_in[9];
  const float* dbhh = (const float*)d_in[10];
  const float* outW = (const float*)d_in[11];
  const float* outb = (const float*)d_in[12];
  float* out = (float*)d_out;

  char* p = (char*)d_ws;
  auto alloc = [&](size_t n){ char* r = p; p += (n + 255) & ~(size_t)255; return r; };
  _Float16* oWh  = (_Float16*)alloc((size_t)VV*1024*2);
  float*    giE  = (float*)alloc((size_t)2560*1536*4);
  float*    giD  = (float*)alloc((size_t)2560*1536*4);
  u64*      hx   = (u64*)alloc((size_t)2*32*128*8);
  _Float16* comb = (_Float16*)alloc((size_t)2560*1024*2);

  prep_all<<<996, 256, 0, stream>>>(src, tgt, emb, eWih, ebih, dWih, dbih,
                                    outW, oWh, giE, giD, hx);
  hipFuncSetAttribute((const void*)seq_pb,
                      hipFuncAttributeMaxDynamicSharedMemorySize, SEQ_SMEM);
  seq_pb<<<256, 512, SEQ_SMEM, stream>>>(eWhh, dWhh, ebhh, dbhh, giE, giD,
                                         hx, comb);
  logits_gemm<<<5120, 256, 0, stream>>>(comb, oWh, outb, out);
}